// Round 1
// baseline (283.174 us; speedup 1.0000x reference)
//
#include <hip/hip_runtime.h>

#define CHUNK 2048
#define WIN   256

// K1: per-row dot products. Wave handles 4 rows/iter with fully coalesced
// float4 loads: lane l reads float4 index rb*16 + l (contiguous 1KB/wave/instr).
__global__ __launch_bounds__(256) void dlm_dots(
    const float* __restrict__ X, const float* __restrict__ Z,
    const float* __restrict__ eta, const float* __restrict__ zeta,
    const float* __restrict__ gam,
    float* __restrict__ base_out, float* __restrict__ c_out, int T)
{
    const int lane = threadIdx.x & 63;
    const int sub  = lane & 15;   // which float4 of the 64-float row
    const int rsub = lane >> 4;   // which of the 4 rows this group handles
    const int gwave = (blockIdx.x * blockDim.x + threadIdx.x) >> 6;
    const int nwave = (gridDim.x * blockDim.x) >> 6;

    const float4 e4 = ((const float4*)eta)[sub];
    const float4 s4 = ((const float4*)zeta)[sub];
    const float4 g4 = ((const float4*)gam)[sub];

    const float4* X4 = (const float4*)X;
    const float4* Z4 = (const float4*)Z;

    for (int rb = gwave * 4; rb < T; rb += nwave * 4) {
        const int row = rb + rsub;
        if (row < T) {                       // uniform within each 16-lane group
            const int idx = rb * 16 + lane;  // contiguous across the wave
            float4 x = X4[idx];
            float4 z = Z4[idx];
            float b = x.x*e4.x + x.y*e4.y + x.z*e4.z + x.w*e4.w
                    + z.x*s4.x + z.y*s4.y + z.z*s4.z + z.w*s4.w;
            float c = z.x*g4.x + z.y*g4.y + z.z*g4.z + z.w*g4.w;
            #pragma unroll
            for (int off = 8; off >= 1; off >>= 1) {
                b += __shfl_xor(b, off, 64);
                c += __shfl_xor(c, off, 64);
            }
            if (sub == 0) {
                base_out[row] = b;
                c_out[row]    = c;
            }
        }
    }
}

// K2: theta scan. Each block owns a CHUNK of rows. Incoming state is computed
// from a WIN-element geometric lookback window (a = sigmoid(G) < 0.7311, so
// a^254 < 1e-34: truncation error is far below f32 eps). Then per-thread
// 8-element segments + Hillis-Steele block scan with ratio a^8.
__global__ __launch_bounds__(256) void dlm_scan(
    const float* __restrict__ c, const float* __restrict__ Gp,
    float* __restrict__ out, int T)
{
    const int tid = threadIdx.x;
    const int s   = blockIdx.x * CHUNK;

    const float g = *Gp;
    const float a = 1.0f / (1.0f + expf(-g));

    __shared__ float cl[WIN + CHUNK];
    __shared__ float red[256];
    __shared__ float sc[256];

    for (int i = tid; i < WIN + CHUNK; i += 256) {
        int t = s - WIN + i;
        cl[i] = (t >= 0 && t < T) ? c[t] : 0.0f;
    }
    __syncthreads();

    // theta_{s-1} = sum_{j>=0} a^j * c[s-2-j]   (truncated at j = WIN-2)
    float term = 0.0f;
    if (tid <= WIN - 2) {
        term = powf(a, (float)tid) * cl[WIN - 2 - tid];
    }
    red[tid] = term;
    __syncthreads();
    #pragma unroll
    for (int off = 128; off > 0; off >>= 1) {
        if (tid < off) red[tid] += red[tid + off];
        __syncthreads();
    }
    const float theta_in = red[0];

    // per-thread segment aggregate: s_i = sum_j a^{7-j} v_{s+8i+j},  v_t = c[t-1], v_0 = 0
    const float a2 = a * a, a4 = a2 * a2, A8 = a4 * a4;
    const int p0 = tid * 8;
    float sl = 0.0f;
    #pragma unroll
    for (int j = 0; j < 8; ++j) {
        int t = s + p0 + j;
        float v = (t == 0) ? 0.0f : cl[WIN + p0 + j - 1];
        sl = a * sl + v;
    }
    sc[tid] = sl;
    __syncthreads();

    // inclusive Hillis-Steele scan with ratio A8 (factor squares each step)
    float Ad = A8;
    for (int d = 1; d < 256; d <<= 1) {
        float self = sc[tid];
        float prev = (tid >= d) ? sc[tid - d] : 0.0f;
        __syncthreads();
        sc[tid] = self + Ad * prev;
        __syncthreads();
        Ad *= Ad;
    }

    const float E = (tid > 0) ? sc[tid - 1] : 0.0f;   // exclusive scan
    float theta = powf(A8, (float)tid) * theta_in + E;
    #pragma unroll
    for (int j = 0; j < 8; ++j) {
        int t = s + p0 + j;
        if (t < T) {
            float v = (t == 0) ? 0.0f : cl[WIN + p0 + j - 1];
            theta = a * theta + v;
            out[t] += theta;   // out already holds X@eta + Z@zeta from K1
        }
    }
}

extern "C" void kernel_launch(void* const* d_in, const int* in_sizes, int n_in,
                              void* d_out, int out_size, void* d_ws, size_t ws_size,
                              hipStream_t stream) {
    const float* X     = (const float*)d_in[0];
    const float* Z     = (const float*)d_in[1];
    const float* G     = (const float*)d_in[2];
    const float* eta   = (const float*)d_in[3];
    const float* zeta  = (const float*)d_in[4];
    const float* gamma = (const float*)d_in[5];
    float* out = (float*)d_out;
    float* c_ws = (float*)d_ws;   // T floats = 2 MB

    const int T = in_sizes[0] / 64;

    dlm_dots<<<2048, 256, 0, stream>>>(X, Z, eta, zeta, gamma, out, c_ws, T);

    const int nchunks = (T + CHUNK - 1) / CHUNK;
    dlm_scan<<<nchunks, 256, 0, stream>>>(c_ws, G, out, T);
}

// Round 3
// 278.589 us; speedup vs baseline: 1.0165x; 1.0165x over previous
//
#include <hip/hip_runtime.h>

// Fully fused DynamicLinearModel kernel.
//
// theta_t = a*theta_{t-1} + c_{t-1},  a = sigmoid(G), c = Z@gamma, theta_0 = 0
// out_t   = theta_t + X_t@eta + Z_t@zeta
//
// Chunks of CHUNK rows are fully independent thanks to a WIN-row geometric
// lookback: a < sigmoid(1) = 0.7311 => a^63 < 3e-9, far below f32 noise.
// Each block recomputes c for its window (6.25% extra Z reads) so there is
// NO inter-kernel dependency, NO workspace, and every d_out element is
// written exactly once from freshly computed values (state-independent).

#define WIN    64
#define CHUNK  1024
#define SEG    4                                   // CHUNK / 256
#define RPI    64                                  // rows per block-iteration
#define NITER  ((WIN + CHUNK) / RPI)               // 17

__global__ __launch_bounds__(256) void dlm_fused(
    const float* __restrict__ X, const float* __restrict__ Z,
    const float* __restrict__ Gp,
    const float* __restrict__ eta, const float* __restrict__ zeta,
    const float* __restrict__ gam,
    float* __restrict__ out, int T)
{
    const int tid  = threadIdx.x;
    const int lane = tid & 63;
    const int wv   = tid >> 6;        // wave 0..3
    const int sub  = lane & 15;       // float4 index within a 64-float row
    const int rsub = lane >> 4;       // row group within the wave (0..3)
    const int s    = (int)blockIdx.x * CHUNK;

    __shared__ float cl[WIN + CHUNK]; // c for rows [s-WIN, s+CHUNK)
    __shared__ float bl[CHUNK];       // base for rows [s, s+CHUNK)
    __shared__ float sc[256];
    __shared__ float theta_sh;

    const float4 e4  = ((const float4*)eta)[sub];
    const float4 sz4 = ((const float4*)zeta)[sub];
    const float4 g4  = ((const float4*)gam)[sub];
    const float4* X4 = (const float4*)X;
    const float4* Z4 = (const float4*)Z;

    const float g   = *Gp;
    const float a   = 1.0f / (1.0f + expf(-g));
    const float l2a = log2f(a);

    // ---- row loop: iteration i covers rows [s-WIN+i*64, s-WIN+(i+1)*64).
    // i == 0 is the pure lookback window (c only, no X / base).
    // 16 lanes per row (perfect 1KB coalescing), 8 loads in flight per thread.
    for (int i = 0; i < NITER; ++i) {
        const int rb = s - WIN + i * RPI + wv * 16;
        float cp[4], bp[4];
        #pragma unroll
        for (int u = 0; u < 4; ++u) {
            const int r = rb + u * 4 + rsub;
            float4 z = make_float4(0.f, 0.f, 0.f, 0.f);
            float4 x = make_float4(0.f, 0.f, 0.f, 0.f);
            const bool in = (r >= 0) && (r < T);
            if (in)           z = Z4[(size_t)r * 16 + sub];
            if (in && i > 0)  x = X4[(size_t)r * 16 + sub];
            cp[u] = z.x*g4.x + z.y*g4.y + z.z*g4.z + z.w*g4.w;
            bp[u] = x.x*e4.x + x.y*e4.y + x.z*e4.z + x.w*e4.w
                  + z.x*sz4.x + z.y*sz4.y + z.z*sz4.z + z.w*sz4.w;
        }
        #pragma unroll
        for (int u = 0; u < 4; ++u) {
            #pragma unroll
            for (int off = 1; off <= 8; off <<= 1) {   // reduce within 16 lanes
                cp[u] += __shfl_xor(cp[u], off, 64);
                bp[u] += __shfl_xor(bp[u], off, 64);
            }
        }
        if (sub == 0) {
            #pragma unroll
            for (int u = 0; u < 4; ++u) {
                const int r = rb + u * 4 + rsub;
                cl[r - s + WIN] = cp[u];          // rows >= T wrote 0
                if (i > 0) bl[r - s] = bp[u];
            }
        }
    }
    __syncthreads();

    // ---- incoming state: theta_{s-1} = sum_{j=0..WIN-2} a^j * c[s-2-j]
    if (tid < 64) {
        float term = 0.0f;
        if (tid <= WIN - 2)
            term = exp2f((float)tid * l2a) * cl[WIN - 2 - tid];
        #pragma unroll
        for (int off = 1; off <= 32; off <<= 1)
            term += __shfl_xor(term, off, 64);
        if (tid == 0) theta_sh = term;
    }

    // ---- per-thread segment aggregate over SEG elements: v_t = c[t-1], v_0 = 0
    const float a2 = a * a, A4 = a2 * a2;
    const int p0 = tid * SEG;
    float sl = 0.0f;
    #pragma unroll
    for (int j = 0; j < SEG; ++j) {
        const int t = s + p0 + j;
        const float v = (t == 0) ? 0.0f : cl[WIN + p0 + j - 1];
        sl = a * sl + v;
    }
    sc[tid] = sl;
    __syncthreads();
    const float theta_in = theta_sh;

    // ---- inclusive Hillis-Steele scan, ratio A4 (squares each step)
    float Ad = A4;
    for (int d = 1; d < 256; d <<= 1) {
        const float self = sc[tid];
        const float prev = (tid >= d) ? sc[tid - d] : 0.0f;
        __syncthreads();
        sc[tid] = self + Ad * prev;
        __syncthreads();
        Ad *= Ad;
    }

    // ---- emit: theta walk over the segment, single coalesced float4 store
    const float E = (tid > 0) ? sc[tid - 1] : 0.0f;
    float theta = exp2f((float)(SEG * tid) * l2a) * theta_in + E;
    float res[SEG];
    #pragma unroll
    for (int j = 0; j < SEG; ++j) {
        const int t = s + p0 + j;
        const float v = (t == 0) ? 0.0f : cl[WIN + p0 + j - 1];
        theta = a * theta + v;
        res[j] = bl[p0 + j] + theta;
    }
    const int t0 = s + p0;
    if (t0 + SEG <= T) {
        ((float4*)out)[(s >> 2) + tid] = make_float4(res[0], res[1], res[2], res[3]);
    } else {
        #pragma unroll
        for (int j = 0; j < SEG; ++j)
            if (t0 + j < T) out[t0 + j] = res[j];
    }
}

extern "C" void kernel_launch(void* const* d_in, const int* in_sizes, int n_in,
                              void* d_out, int out_size, void* d_ws, size_t ws_size,
                              hipStream_t stream) {
    const float* X     = (const float*)d_in[0];
    const float* Z     = (const float*)d_in[1];
    const float* G     = (const float*)d_in[2];
    const float* eta   = (const float*)d_in[3];
    const float* zeta  = (const float*)d_in[4];
    const float* gamma = (const float*)d_in[5];
    float* out = (float*)d_out;

    const int T = in_sizes[0] / 64;
    const int nblk = (T + CHUNK - 1) / CHUNK;

    dlm_fused<<<nblk, 256, 0, stream>>>(X, Z, G, eta, zeta, gamma, out, T);
}